// Round 1
// baseline (217.343 us; speedup 1.0000x reference)
//
#include <hip/hip_runtime.h>
#include <math.h>

// Problem constants (match reference)
#define BB      8
#define C_CH    128
#define HH      256
#define WW      256
#define N_POS   2048
#define N_NEG   8192
#define N_ROWS  (N_POS + N_NEG)     // 10240
#define EPS_N   1e-6f

// sim-kernel tiling
#define TI      64
#define TJ      64
#define NIB     (N_POS / TI)        // 32
#define NJB     (N_ROWS / TJ)       // 160
#define NJB_POS (N_POS / TJ)        // 32
#define LDSPAD  129                 // 128 + 1: breaks pow2 bank stride

// Workspace layout (floats):
//   norm:    [N_ROWS][128]            @ 0            (10240*128 = 1,310,720 f)
//   partial: [NJB][N_POS]             @ 1,310,720    (160*2048  =   327,680 f)
// total ~6.25 MB

// ---------------------------------------------------------------------------
// Kernel 1: gather channel vectors at (b,:,h,w), L2-normalize, store row-major.
// One wave per row; lane l owns channels l and l+64.
__global__ __launch_bounds__(256) void gather_norm_kernel(
    const float* __restrict__ seg,
    const int* __restrict__ pb, const int* __restrict__ ph, const int* __restrict__ pw,
    const int* __restrict__ nb, const int* __restrict__ nh, const int* __restrict__ nw,
    float* __restrict__ norm)
{
    const int wave = threadIdx.x >> 6;
    const int lane = threadIdx.x & 63;
    const int row  = blockIdx.x * 4 + wave;
    if (row >= N_ROWS) return;

    int b, h, w;
    if (row < N_POS) { b = pb[row]; h = ph[row]; w = pw[row]; }
    else { const int r = row - N_POS; b = nb[r]; h = nh[r]; w = nw[r]; }

    const size_t cs   = (size_t)HH * WW;                 // channel stride
    const size_t base = (size_t)b * C_CH * cs + (size_t)h * WW + (size_t)w;

    const float v0 = seg[base + (size_t)lane * cs];
    const float v1 = seg[base + (size_t)(lane + 64) * cs];

    float ss = v0 * v0 + v1 * v1;
#pragma unroll
    for (int m = 1; m < 64; m <<= 1) ss += __shfl_xor(ss, m, 64);

    float n = fmaxf(sqrtf(ss), EPS_N);
    norm[(size_t)row * C_CH + lane]      = v0 / n;
    norm[(size_t)row * C_CH + lane + 64] = v1 / n;
}

// ---------------------------------------------------------------------------
// Kernel 2: tile (ib: 64 pos rows) x (jb: 64 cols from all 10240 rows).
// acc[4][4] per thread, K=128 fully resident in LDS.
// Epilogue: expf, reduce the 64 columns of the tile per pos row, write one
// partial per (jb, row) -- written exactly once => deterministic.
__global__ __launch_bounds__(256) void sim_kernel(
    const float* __restrict__ norm, float* __restrict__ partial)
{
    const int ib = blockIdx.x;   // 0..NIB-1
    const int jb = blockIdx.y;   // 0..NJB-1

    __shared__ float lA[TI * LDSPAD];
    __shared__ float lB[TJ * LDSPAD];

    const int t = threadIdx.x;

    // Stage both tiles: coalesced float4 global reads, scalar LDS writes.
    for (int q = t; q < TI * C_CH / 4; q += 256) {
        const int f = q * 4;
        const int i = f >> 7;          // row within tile
        const int k = f & 127;         // channel
        const float4 a = *(const float4*)&norm[((size_t)(ib * TI + i)) * C_CH + k];
        float* da = &lA[i * LDSPAD + k];
        da[0] = a.x; da[1] = a.y; da[2] = a.z; da[3] = a.w;
        const float4 bv = *(const float4*)&norm[((size_t)(jb * TJ + i)) * C_CH + k];
        float* db = &lB[i * LDSPAD + k];
        db[0] = bv.x; db[1] = bv.y; db[2] = bv.z; db[3] = bv.w;
    }
    __syncthreads();

    const int ti = t >> 4;   // 0..15 -> pos rows ti*4 .. ti*4+3
    const int tj = t & 15;   // 0..15 -> cols    tj*4 .. tj*4+3

    float acc[4][4] = {{0.f}};
    const float* pa = &lA[ti * 4 * LDSPAD];
    const float* pb2 = &lB[tj * 4 * LDSPAD];

#pragma unroll 4
    for (int k = 0; k < 128; ++k) {
        const float a0 = pa[k];
        const float a1 = pa[LDSPAD + k];
        const float a2 = pa[2 * LDSPAD + k];
        const float a3 = pa[3 * LDSPAD + k];
        const float b0 = pb2[k];
        const float b1 = pb2[LDSPAD + k];
        const float b2 = pb2[2 * LDSPAD + k];
        const float b3 = pb2[3 * LDSPAD + k];
        acc[0][0] = fmaf(a0, b0, acc[0][0]);
        acc[0][1] = fmaf(a0, b1, acc[0][1]);
        acc[0][2] = fmaf(a0, b2, acc[0][2]);
        acc[0][3] = fmaf(a0, b3, acc[0][3]);
        acc[1][0] = fmaf(a1, b0, acc[1][0]);
        acc[1][1] = fmaf(a1, b1, acc[1][1]);
        acc[1][2] = fmaf(a1, b2, acc[1][2]);
        acc[1][3] = fmaf(a1, b3, acc[1][3]);
        acc[2][0] = fmaf(a2, b0, acc[2][0]);
        acc[2][1] = fmaf(a2, b1, acc[2][1]);
        acc[2][2] = fmaf(a2, b2, acc[2][2]);
        acc[2][3] = fmaf(a2, b3, acc[2][3]);
        acc[3][0] = fmaf(a3, b0, acc[3][0]);
        acc[3][1] = fmaf(a3, b1, acc[3][1]);
        acc[3][2] = fmaf(a3, b2, acc[3][2]);
        acc[3][3] = fmaf(a3, b3, acc[3][3]);
    }

    // exp + per-pos-row sum across this tile's 64 columns.
#pragma unroll
    for (int r = 0; r < 4; ++r) {
        float s = expf(acc[r][0]) + expf(acc[r][1]) + expf(acc[r][2]) + expf(acc[r][3]);
        s += __shfl_xor(s, 1, 64);
        s += __shfl_xor(s, 2, 64);
        s += __shfl_xor(s, 4, 64);
        s += __shfl_xor(s, 8, 64);
        if (tj == 0) {
            const int row = ib * TI + ti * 4 + r;
            partial[(size_t)jb * N_POS + row] = s;
        }
    }
}

// ---------------------------------------------------------------------------
// Kernel 3: single block => deterministic final reduction.
__global__ __launch_bounds__(256) void finalize_kernel(
    const float* __restrict__ partial, float* __restrict__ out)
{
    const int t = threadIdx.x;
    const float E1 = 2.71828182845904523536f;   // exp(1)
    float local = 0.f;

    for (int i = t; i < N_POS; i += 256) {
        float P = 0.f, Nv = 0.f;
        for (int jb = 0; jb < NJB_POS; ++jb)     P  += partial[(size_t)jb * N_POS + i];
        for (int jb = NJB_POS; jb < NJB; ++jb)   Nv += partial[(size_t)jb * N_POS + i];
        const float p = P - E1;                  // pos_row_sum (self-sim removed)
        local += logf(p) - logf(p + Nv);
    }

    __shared__ float red[256];
    red[t] = local;
    __syncthreads();
    for (int s = 128; s > 0; s >>= 1) {
        if (t < s) red[t] += red[t + s];
        __syncthreads();
    }
    if (t == 0) out[0] = -red[0] / (float)N_POS;
}

// ---------------------------------------------------------------------------
extern "C" void kernel_launch(void* const* d_in, const int* in_sizes, int n_in,
                              void* d_out, int out_size, void* d_ws, size_t ws_size,
                              hipStream_t stream)
{
    const float* seg = (const float*)d_in[0];
    const int* pb = (const int*)d_in[1];
    const int* ph = (const int*)d_in[2];
    const int* pw = (const int*)d_in[3];
    const int* nb = (const int*)d_in[4];
    const int* nh = (const int*)d_in[5];
    const int* nw = (const int*)d_in[6];
    float* out = (float*)d_out;

    float* norm    = (float*)d_ws;                       // 10240*128 floats
    float* partial = norm + (size_t)N_ROWS * C_CH;       // 160*2048 floats

    // 1) gather + L2-normalize
    gather_norm_kernel<<<dim3((N_ROWS + 3) / 4), dim3(256), 0, stream>>>(
        seg, pb, ph, pw, nb, nh, nw, norm);

    // 2) similarity tiles + exp + per-tile row sums
    sim_kernel<<<dim3(NIB, NJB), dim3(256), 0, stream>>>(norm, partial);

    // 3) final reduction (single block, deterministic)
    finalize_kernel<<<dim3(1), dim3(256), 0, stream>>>(partial, out);
}

// Round 2
// 106.338 us; speedup vs baseline: 2.0439x; 2.0439x over previous
//
#include <hip/hip_runtime.h>
#include <math.h>

// Problem constants (match reference)
#define BB      8
#define C_CH    128
#define HH      256
#define WW      256
#define N_POS   2048
#define N_NEG   8192
#define N_ROWS  (N_POS + N_NEG)     // 10240
#define EPS_N   1e-6f

// sim-kernel tiling: 128x128 tile, 8x8 per thread, K staged in chunks of 32
#define TI      128
#define TJ      128
#define KC      32
#define IPAD    132                 // 128 + 4: keeps 16B alignment, breaks pow2 stride
#define NIB     (N_POS / TI)        // 16
#define NJB     (N_ROWS / TJ)       // 80
#define NJB_POS (N_POS / TJ)        // 16

// Workspace layout (floats):
//   norm:    [N_ROWS][128]   @ 0                       (1,310,720 f)
//   partial: [NJB][N_POS]    @ 1,310,720               (  163,840 f)
//   term:    [N_POS]         @ 1,474,560               (    2,048 f)

// ---------------------------------------------------------------------------
// Kernel 1: gather channel vectors at (b,:,h,w), L2-normalize, store row-major.
// One wave per row; lane l owns channels l and l+64.
__global__ __launch_bounds__(256) void gather_norm_kernel(
    const float* __restrict__ seg,
    const int* __restrict__ pb, const int* __restrict__ ph, const int* __restrict__ pw,
    const int* __restrict__ nb, const int* __restrict__ nh, const int* __restrict__ nw,
    float* __restrict__ norm)
{
    const int wave = threadIdx.x >> 6;
    const int lane = threadIdx.x & 63;
    const int row  = blockIdx.x * 4 + wave;
    if (row >= N_ROWS) return;

    int b, h, w;
    if (row < N_POS) { b = pb[row]; h = ph[row]; w = pw[row]; }
    else { const int r = row - N_POS; b = nb[r]; h = nh[r]; w = nw[r]; }

    const size_t cs   = (size_t)HH * WW;
    const size_t base = (size_t)b * C_CH * cs + (size_t)h * WW + (size_t)w;

    const float v0 = seg[base + (size_t)lane * cs];
    const float v1 = seg[base + (size_t)(lane + 64) * cs];

    float ss = v0 * v0 + v1 * v1;
#pragma unroll
    for (int m = 1; m < 64; m <<= 1) ss += __shfl_xor(ss, m, 64);

    const float n = fmaxf(sqrtf(ss), EPS_N);
    norm[(size_t)row * C_CH + lane]      = v0 / n;
    norm[(size_t)row * C_CH + lane + 64] = v1 / n;
}

// ---------------------------------------------------------------------------
// Kernel 2: C[i][j] = dot(norm[i], norm[j]) over 128x128 tiles, 8x8 per thread.
// LDS tiles are k-major (transposed): lAT[k][i], lBT[k][j] so each thread's
// operands are two contiguous float4 per array per k (ds_read_b128, <=2-way
// bank aliasing = free). Epilogue: exp + per-row sum over the tile's 128 cols,
// one partial per (jb,row), written exactly once => deterministic.
__global__ __launch_bounds__(256, 3) void sim_kernel(
    const float* __restrict__ norm, float* __restrict__ partial)
{
    __shared__ __align__(16) float lAT[KC][IPAD];
    __shared__ __align__(16) float lBT[KC][IPAD];

    const int t  = threadIdx.x;
    const int ib = blockIdx.x;   // 0..NIB-1  (pos rows)
    const int jb = blockIdx.y;   // 0..NJB-1  (all rows)
    const size_t i0 = (size_t)ib * TI;
    const size_t j0 = (size_t)jb * TJ;

    const int ti = t >> 4;       // 0..15
    const int tj = t & 15;       // 0..15

    float acc[8][8];
#pragma unroll
    for (int r = 0; r < 8; ++r)
#pragma unroll
        for (int c = 0; c < 8; ++c) acc[r][c] = 0.f;

    for (int kc = 0; kc < C_CH; kc += KC) {
        if (kc) __syncthreads();
        // Stage: coalesced 64B-line global reads, 2-way-only LDS writes.
#pragma unroll
        for (int it = 0; it < 4; ++it) {
            const int kq = (t & 3) + 4 * (it & 1);        // 0..7 float4 within chunk
            const int i  = (t >> 2) + 64 * (it >> 1);     // 0..127 row within tile
            const float4 av = *(const float4*)&norm[(i0 + i) * C_CH + kc + kq * 4];
            const float4 bv = *(const float4*)&norm[(j0 + i) * C_CH + kc + kq * 4];
            lAT[kq*4+0][i] = av.x; lAT[kq*4+1][i] = av.y;
            lAT[kq*4+2][i] = av.z; lAT[kq*4+3][i] = av.w;
            lBT[kq*4+0][i] = bv.x; lBT[kq*4+1][i] = bv.y;
            lBT[kq*4+2][i] = bv.z; lBT[kq*4+3][i] = bv.w;
        }
        __syncthreads();

#pragma unroll 4
        for (int k = 0; k < KC; ++k) {
            const float4 a0 = *(const float4*)&lAT[k][ti * 4];
            const float4 a1 = *(const float4*)&lAT[k][ti * 4 + 64];
            const float4 b0 = *(const float4*)&lBT[k][tj * 4];
            const float4 b1 = *(const float4*)&lBT[k][tj * 4 + 64];
            const float a[8] = {a0.x, a0.y, a0.z, a0.w, a1.x, a1.y, a1.z, a1.w};
            const float b[8] = {b0.x, b0.y, b0.z, b0.w, b1.x, b1.y, b1.z, b1.w};
#pragma unroll
            for (int r = 0; r < 8; ++r)
#pragma unroll
                for (int c = 0; c < 8; ++c)
                    acc[r][c] = fmaf(a[r], b[c], acc[r][c]);
        }
    }

    // Epilogue: exp + per-pos-row sum across this tile's 128 columns.
#pragma unroll
    for (int r = 0; r < 8; ++r) {
        float s = 0.f;
#pragma unroll
        for (int c = 0; c < 8; ++c) s += expf(acc[r][c]);
        s += __shfl_xor(s, 1, 64);
        s += __shfl_xor(s, 2, 64);
        s += __shfl_xor(s, 4, 64);
        s += __shfl_xor(s, 8, 64);
        if (tj == 0) {
            const int il = (r < 4) ? (ti * 4 + r) : (64 + ti * 4 + (r - 4));
            partial[(size_t)jb * N_POS + i0 + il] = s;
        }
    }
}

// ---------------------------------------------------------------------------
// Kernel 3a: per-row reduction over the 80 jb partials (8 blocks, coalesced).
__global__ __launch_bounds__(256) void rowred_kernel(
    const float* __restrict__ partial, float* __restrict__ term)
{
    const int row = blockIdx.x * 256 + threadIdx.x;
    float P = 0.f, Nv = 0.f;
    for (int jb = 0; jb < NJB_POS; ++jb)   P  += partial[(size_t)jb * N_POS + row];
    for (int jb = NJB_POS; jb < NJB; ++jb) Nv += partial[(size_t)jb * N_POS + row];
    const float p = P - 2.71828182845904523536f;   // remove self-sim exp(1)
    term[row] = logf(p) - logf(p + Nv);
}

// Kernel 3b: single tiny block => deterministic final mean.
__global__ __launch_bounds__(256) void final_kernel(
    const float* __restrict__ term, float* __restrict__ out)
{
    const int t = threadIdx.x;
    float local = 0.f;
    for (int i = t; i < N_POS; i += 256) local += term[i];

    __shared__ float red[256];
    red[t] = local;
    __syncthreads();
    for (int s = 128; s > 0; s >>= 1) {
        if (t < s) red[t] += red[t + s];
        __syncthreads();
    }
    if (t == 0) out[0] = -red[0] / (float)N_POS;
}

// ---------------------------------------------------------------------------
extern "C" void kernel_launch(void* const* d_in, const int* in_sizes, int n_in,
                              void* d_out, int out_size, void* d_ws, size_t ws_size,
                              hipStream_t stream)
{
    const float* seg = (const float*)d_in[0];
    const int* pb = (const int*)d_in[1];
    const int* ph = (const int*)d_in[2];
    const int* pw = (const int*)d_in[3];
    const int* nb = (const int*)d_in[4];
    const int* nh = (const int*)d_in[5];
    const int* nw = (const int*)d_in[6];
    float* out = (float*)d_out;

    float* norm    = (float*)d_ws;                        // 10240*128
    float* partial = norm + (size_t)N_ROWS * C_CH;        // 80*2048
    float* term    = partial + (size_t)NJB * N_POS;       // 2048

    gather_norm_kernel<<<dim3((N_ROWS + 3) / 4), dim3(256), 0, stream>>>(
        seg, pb, ph, pw, nb, nh, nw, norm);

    sim_kernel<<<dim3(NIB, NJB), dim3(256), 0, stream>>>(norm, partial);

    rowred_kernel<<<dim3(N_POS / 256), dim3(256), 0, stream>>>(partial, term);
    final_kernel<<<dim3(1), dim3(256), 0, stream>>>(term, out);
}

// Round 7
// 86.660 us; speedup vs baseline: 2.5080x; 1.2271x over previous
//
#include <hip/hip_runtime.h>
#include <hip/hip_bf16.h>
#include <math.h>

// Problem constants (match reference)
#define BB      8
#define C_CH    128
#define HH      256
#define WW      256
#define N_POS   2048
#define N_NEG   8192
#define N_ROWS  (N_POS + N_NEG)     // 10240
#define EPS_N   1e-6f

// sim tiling: block = 4 waves as 2x2, each wave 64x64 output, K=128 in 4 steps
#define NIB     (N_POS / 128)       // 16
#define NJB     (N_ROWS / 128)      // 80
#define NJSLAB      (N_ROWS / 64)   // 160 j-slabs of 64 cols (per-wave extent)
#define NJSLAB_POS  (N_POS / 64)    // 32

typedef __attribute__((ext_vector_type(8))) short bf16x8;   // 8 bf16 = 4 VGPR
typedef __attribute__((ext_vector_type(4))) float f32x4;    // MFMA C/D

// Workspace layout:
//   hi:      [N_ROWS][128] bf16   @ 0              (2.62 MB)
//   lo:      [N_ROWS][128] bf16   @ 2.62 MB        (2.62 MB)
//   partial: [NJSLAB][N_POS] f32                   (1.31 MB)
//   term:    [N_POS] f32                           (8 KB)

// ---------------------------------------------------------------------------
// Kernel 1: gather channel vectors at (b,:,h,w), L2-normalize in fp32, then
// split each normalized value into bf16 hi + bf16 lo (x ~= hi + lo).
// One wave per row; lane l owns channels l and l+64.
__global__ __launch_bounds__(256) void gather_norm_kernel(
    const float* __restrict__ seg,
    const int* __restrict__ pb, const int* __restrict__ ph, const int* __restrict__ pw,
    const int* __restrict__ nb, const int* __restrict__ nh, const int* __restrict__ nw,
    __hip_bfloat16* __restrict__ hi, __hip_bfloat16* __restrict__ lo)
{
    const int wave = threadIdx.x >> 6;
    const int lane = threadIdx.x & 63;
    const int row  = blockIdx.x * 4 + wave;
    if (row >= N_ROWS) return;

    int b, h, w;
    if (row < N_POS) { b = pb[row]; h = ph[row]; w = pw[row]; }
    else { const int r = row - N_POS; b = nb[r]; h = nh[r]; w = nw[r]; }

    const size_t cs   = (size_t)HH * WW;
    const size_t base = (size_t)b * C_CH * cs + (size_t)h * WW + (size_t)w;

    const float v0 = seg[base + (size_t)lane * cs];
    const float v1 = seg[base + (size_t)(lane + 64) * cs];

    float ss = v0 * v0 + v1 * v1;
#pragma unroll
    for (int m = 1; m < 64; m <<= 1) ss += __shfl_xor(ss, m, 64);

    const float n  = fmaxf(sqrtf(ss), EPS_N);
    const float u0 = v0 / n;
    const float u1 = v1 / n;

    const __hip_bfloat16 h0 = __float2bfloat16(u0);
    const __hip_bfloat16 h1 = __float2bfloat16(u1);
    const __hip_bfloat16 l0 = __float2bfloat16(u0 - __bfloat162float(h0));
    const __hip_bfloat16 l1 = __float2bfloat16(u1 - __bfloat162float(h1));

    const size_t o = (size_t)row * C_CH + lane;
    hi[o]      = h0;  lo[o]      = l0;
    hi[o + 64] = h1;  lo[o + 64] = l1;
}

// ---------------------------------------------------------------------------
// Kernel 2: C[i][j] = dot(x_i, x_j) via 3-term split-bf16 MFMA
// (hi*hi + hi*lo + lo*hi; missing lo*lo <= 2^-18 relative).
// No LDS: fragments load straight from global (L2/L3-resident, 5.2 MB set).
// Both operands are row-major [row][k], i.e. the "B^T" fragment case: lane l
// reads 8 contiguous bf16 at row (l&15), k-chunk (l>>4) -- identical for A & B.
// Epilogue: exp + per-row sum over the wave's 64 cols; one write per
// (jslab,row) => deterministic.
__global__ __launch_bounds__(256, 2) void sim_mfma_kernel(
    const __hip_bfloat16* __restrict__ hi_, const __hip_bfloat16* __restrict__ lo_,
    float* __restrict__ partial)
{
    const ushort* __restrict__ hi = (const ushort*)hi_;
    const ushort* __restrict__ lo = (const ushort*)lo_;

    const int bid = blockIdx.x;
    const int ib  = bid / NJB;          // 0..15
    const int jb  = bid % NJB;          // 0..79  (ids sharing jb are == mod 8 -> same XCD)
    const int t    = threadIdx.x;
    const int wave = t >> 6;
    const int lane = t & 63;
    const int wy = wave >> 1;           // i-half
    const int wx = wave & 1;            // j-half

    const int iw0 = ib * 128 + wy * 64;
    const int jw0 = jb * 128 + wx * 64;

    const int lr = lane & 15;           // row/col within 16x16 tile
    const int lk = lane >> 4;           // k-chunk (8 bf16)

    f32x4 acc[4][4];
#pragma unroll
    for (int m = 0; m < 4; ++m)
#pragma unroll
        for (int n = 0; n < 4; ++n) acc[m][n] = (f32x4){0.f, 0.f, 0.f, 0.f};

#pragma unroll
    for (int ks = 0; ks < 4; ++ks) {
        const int koff = ks * 32 + lk * 8;

        bf16x8 ah[4], al[4];
#pragma unroll
        for (int m = 0; m < 4; ++m) {
            const size_t ra = (size_t)(iw0 + m * 16 + lr) * C_CH + koff;
            ah[m] = *(const bf16x8*)&hi[ra];
            al[m] = *(const bf16x8*)&lo[ra];
        }
#pragma unroll
        for (int n = 0; n < 4; ++n) {
            const size_t rb = (size_t)(jw0 + n * 16 + lr) * C_CH + koff;
            const bf16x8 bh = *(const bf16x8*)&hi[rb];
            const bf16x8 bl = *(const bf16x8*)&lo[rb];
#pragma unroll
            for (int m = 0; m < 4; ++m) {
                acc[m][n] = __builtin_amdgcn_mfma_f32_16x16x32_bf16(ah[m], bh, acc[m][n], 0, 0, 0);
                acc[m][n] = __builtin_amdgcn_mfma_f32_16x16x32_bf16(ah[m], bl, acc[m][n], 0, 0, 0);
                acc[m][n] = __builtin_amdgcn_mfma_f32_16x16x32_bf16(al[m], bh, acc[m][n], 0, 0, 0);
            }
        }
    }

    // Epilogue. C/D layout: value r of lane l = C[iw0+m*16+(l>>4)*4+r][jw0+n*16+(l&15)]
    const int jslab = jw0 >> 6;         // 0..159
#pragma unroll
    for (int m = 0; m < 4; ++m) {
        float s0 = 0.f, s1 = 0.f, s2 = 0.f, s3 = 0.f;
#pragma unroll
        for (int n = 0; n < 4; ++n) {
            s0 += expf(acc[m][n][0]);
            s1 += expf(acc[m][n][1]);
            s2 += expf(acc[m][n][2]);
            s3 += expf(acc[m][n][3]);
        }
        float s[4] = {s0, s1, s2, s3};
#pragma unroll
        for (int r = 0; r < 4; ++r) {
            float v = s[r];
            v += __shfl_xor(v, 1, 64);
            v += __shfl_xor(v, 2, 64);
            v += __shfl_xor(v, 4, 64);
            v += __shfl_xor(v, 8, 64);
            if (lr == 0) {
                const int row = iw0 + m * 16 + lk * 4 + r;
                partial[(size_t)jslab * N_POS + row] = v;
            }
        }
    }
}

// ---------------------------------------------------------------------------
// Kernel 3a: per-row reduction over the 160 j-slab partials (coalesced).
__global__ __launch_bounds__(256) void rowred_kernel(
    const float* __restrict__ partial, float* __restrict__ term)
{
    const int row = blockIdx.x * 256 + threadIdx.x;
    float P = 0.f, Nv = 0.f;
    for (int s = 0; s < NJSLAB_POS; ++s)      P  += partial[(size_t)s * N_POS + row];
    for (int s = NJSLAB_POS; s < NJSLAB; ++s) Nv += partial[(size_t)s * N_POS + row];
    const float p = P - 2.71828182845904523536f;   // remove self-sim exp(1)
    term[row] = logf(p) - logf(p + Nv);
}

// Kernel 3b: single block => deterministic final mean.
__global__ __launch_bounds__(256) void final_kernel(
    const float* __restrict__ term, float* __restrict__ out)
{
    const int t = threadIdx.x;
    float local = 0.f;
    for (int i = t; i < N_POS; i += 256) local += term[i];

    __shared__ float red[256];
    red[t] = local;
    __syncthreads();
    for (int s = 128; s > 0; s >>= 1) {
        if (t < s) red[t] += red[t + s];
        __syncthreads();
    }
    if (t == 0) out[0] = -red[0] / (float)N_POS;
}

// ---------------------------------------------------------------------------
extern "C" void kernel_launch(void* const* d_in, const int* in_sizes, int n_in,
                              void* d_out, int out_size, void* d_ws, size_t ws_size,
                              hipStream_t stream)
{
    const float* seg = (const float*)d_in[0];
    const int* pb = (const int*)d_in[1];
    const int* ph = (const int*)d_in[2];
    const int* pw = (const int*)d_in[3];
    const int* nb = (const int*)d_in[4];
    const int* nh = (const int*)d_in[5];
    const int* nw = (const int*)d_in[6];
    float* out = (float*)d_out;

    __hip_bfloat16* hi = (__hip_bfloat16*)d_ws;
    __hip_bfloat16* lo = hi + (size_t)N_ROWS * C_CH;
    float* partial = (float*)(lo + (size_t)N_ROWS * C_CH);
    float* term    = partial + (size_t)NJSLAB * N_POS;

    gather_norm_kernel<<<dim3((N_ROWS + 3) / 4), dim3(256), 0, stream>>>(
        seg, pb, ph, pw, nb, nh, nw, hi, lo);

    sim_mfma_kernel<<<dim3(NIB * NJB), dim3(256), 0, stream>>>(hi, lo, partial);

    rowred_kernel<<<dim3(N_POS / 256), dim3(256), 0, stream>>>(partial, term);
    final_kernel<<<dim3(1), dim3(256), 0, stream>>>(term, out);
}